// Round 1
// baseline (10244.949 us; speedup 1.0000x reference)
//
#include <hip/hip_runtime.h>
#include <math.h>

#define NPTS 65536
#define KP   16
#define DIM  64
#define C2   128
#define EPSV 1e-5f

#define B1G  256   // kernel-1 grid
#define B3G  512   // kernel-3 grid
#define NPB  128   // n per k3 block

// workspace float offsets
#define OFF_P1  0                      // B1G*65
#define OFF_S1  (B1G*65)               // 256 : scale1[128], shift1[128]
#define OFF_P2  (OFF_S1+256)           // B3G*128
#define OFF_S2  (OFF_P2+B3G*128)       // 128 : scale2[64], shift2[64]
#define OFF_PRE (OFF_S2+128)           // NPTS*64

typedef unsigned int u32;

__device__ __forceinline__ u32 f2bf(float f){
  u32 u = __float_as_uint(f);
  return (u + 0x7fffu + ((u>>16)&1u)) >> 16;   // RNE to bf16
}
__device__ __forceinline__ u32 packbf(float a, float b){ return f2bf(a) | (f2bf(b)<<16); }
__device__ __forceinline__ float bflo(u32 u){ return __uint_as_float(u<<16); }
__device__ __forceinline__ float bfhi(u32 u){ return __uint_as_float(u & 0xffff0000u); }

// ---------------- kernel 1: Gram-matrix stats over all N*K rows -------------
// h = concat@w1 (+b1, which cancels in BN). Sum_h = (Sum c)@w1 ; Sum_h2 = w1^T (Sum c c^T) w1.
// Accumulate s[10] and upper-tri M[55] per thread, wave-shuffle reduce, per-block partial out.
__global__ __launch_bounds__(256) void k1_stats(const float* __restrict__ p, float* __restrict__ part1){
  int tid = blockIdx.x*256 + threadIdx.x;
  float M[55]; float s[10];
  #pragma unroll
  for(int i=0;i<55;i++) M[i]=0.f;
  #pragma unroll
  for(int i=0;i<10;i++) s[i]=0.f;
  for(int it=0; it<16; ++it){
    int r = it*65536 + tid;
    int n = r >> 4;
    int kk = r & 15;
    const float* pn = p + (size_t)n*48;
    float cx=pn[0], cy=pn[1], cz=pn[2];
    float ax=pn[kk*3+0], ay=pn[kk*3+1], az=pn[kk*3+2];
    float dx=cx-ax, dy=cy-ay, dz=cz-az;
    float dd = sqrtf(dx*dx+dy*dy+dz*dz);
    float c[10]={cx,cy,cz,ax,ay,az,dx,dy,dz,dd};
    #pragma unroll
    for(int i=0;i<10;i++) s[i]+=c[i];
    int idx=0;
    #pragma unroll
    for(int i=0;i<10;i++){
      #pragma unroll
      for(int j=i;j<10;j++){
        M[idx] = fmaf(c[i],c[j],M[idx]);
        idx++;
      }
    }
  }
  #pragma unroll
  for(int i=0;i<10;i++){
    for(int off=32; off>0; off>>=1) s[i] += __shfl_down(s[i], off, 64);
  }
  #pragma unroll
  for(int i=0;i<55;i++){
    for(int off=32; off>0; off>>=1) M[i] += __shfl_down(M[i], off, 64);
  }
  __shared__ float sm[4][65];
  int lane = threadIdx.x & 63, w = threadIdx.x >> 6;
  if(lane==0){
    #pragma unroll
    for(int i=0;i<10;i++) sm[w][i]=s[i];
    #pragma unroll
    for(int i=0;i<55;i++) sm[w][10+i]=M[i];
  }
  __syncthreads();
  if(threadIdx.x<65){
    float v = sm[0][threadIdx.x]+sm[1][threadIdx.x]+sm[2][threadIdx.x]+sm[3][threadIdx.x];
    part1[blockIdx.x*65 + threadIdx.x] = v;
  }
}

// ---------------- kernel 2: finalize BN1 scale/shift ------------------------
__device__ __forceinline__ int tri_idx(int i,int j){
  int a = i<j? i : j;
  int b = i<j? j : i;
  return 10*a - (a*(a-1))/2 + (b-a);
}
__global__ void k2_fin(const float* __restrict__ part1, const float* __restrict__ w1,
                       const float* __restrict__ g1, const float* __restrict__ be1,
                       float* __restrict__ stats1){
  __shared__ float S[65];
  int t = threadIdx.x; // 128 threads
  if(t<65){
    float a=0.f;
    for(int b=0;b<B1G;b++) a += part1[b*65+t];
    S[t]=a;
  }
  __syncthreads();
  float wc[10];
  #pragma unroll
  for(int c=0;c<10;c++) wc[c]=w1[c*128+t];
  float md=0.f;
  #pragma unroll
  for(int c=0;c<10;c++) md += S[c]*wc[c];
  const float invR = 1.0f/(float)(NPTS*KP);
  md *= invR;
  float q=0.f;
  #pragma unroll
  for(int i=0;i<10;i++){
    float ti=0.f;
    #pragma unroll
    for(int j=0;j<10;j++) ti += S[10+tri_idx(i,j)]*wc[j];
    q = fmaf(ti, wc[i], q);
  }
  q *= invR;
  float var = q - md*md;
  float sc = g1[t]*rsqrtf(var+EPSV);
  float sh = be1[t] - md*sc;            // b1 cancels inside BN
  stats1[t]=sc;
  stats1[128+t]=sh;
}

// ---------------- kernel 3: fused per-n pipeline ----------------------------
// 4 waves/block, one n per wave-iteration; wave-private LDS buffers (no intra-loop barriers).
// lane = 4k+q : k = point index (16), q = channel-chunk (4).
__global__ __launch_bounds__(256,2) void k3_main(
    const float* __restrict__ p, const float* __restrict__ x,
    const float* __restrict__ w2, const float* __restrict__ b2,
    const float* __restrict__ ws_m, const float* __restrict__ wo,
    const float* __restrict__ w1, const float* __restrict__ stats1,
    float* __restrict__ pre, float* __restrict__ part2)
{
  __shared__ __align__(16) float w1s[10*152];      // swizzled: e + 8*(e>>5) breaks 32-stride bank aliasing
  __shared__ __align__(16) float s_sc[128];
  __shared__ __align__(16) float s_sh[128];
  __shared__ __align__(16) float s_b2[64];
  __shared__ __align__(16) float buf1[4][16*132];  // fp32: h, then logits
  __shared__ __align__(16) u32   bpx[4][16*68];    // bf16 p_x (row stride 68 uints = 136 bf16)
  __shared__ __align__(16) float s_feat[4][128];
  __shared__ __align__(16) float s_red[4][128];

  int tid = threadIdx.x;
  for(int i=tid;i<1280;i+=256){
    int c = i>>7, e = i&127;
    w1s[c*152 + e + 8*(e>>5)] = w1[i];
  }
  if(tid<128){ s_sc[tid]=stats1[tid]; s_sh[tid]=stats1[128+tid]; }
  else if(tid<192){ s_b2[tid-128]=b2[tid-128]; }
  __syncthreads();

  const int w    = tid>>6;
  const int lane = tid&63;
  const int k    = lane>>2;
  const int q    = lane&3;
  float* B1p = buf1[w];
  u32*   B2u = bpx[w];
  unsigned short* B2s = (unsigned short*)bpx[w];
  float a_s=0.f, a_q=0.f;

  const float4* w2f4 = (const float4*)w2;
  const float4* wsf4 = (const float4*)ws_m;

  for(int it=0; it<32; ++it){
    int n = blockIdx.x*NPB + it*4 + w;
    // ---- x row -> bf16 LDS (p_x high half), coalesced float4 loads
    const float4* xg = (const float4*)(x + (size_t)n*1024);
    #pragma unroll
    for(int t=0;t<4;t++){
      int f = lane + 64*t;                 // float4 index within the row
      float4 v = xg[f];
      u32 p0 = packbf(v.x,v.y);
      u32 p1 = packbf(v.z,v.w);
      int kk = f>>4, d4 = f&15;
      *(uint2*)&B2u[kk*68 + 32 + 2*d4] = make_uint2(p0,p1);
    }
    // ---- concat geometry (10 features)
    const float* pn = p + (size_t)n*48;
    float cx=pn[0], cy=pn[1], cz=pn[2];
    float ax=pn[k*3+0], ay=pn[k*3+1], az=pn[k*3+2];
    float dx=cx-ax, dy=cy-ay, dz=cz-az;
    float dd=sqrtf(dx*dx+dy*dy+dz*dz);
    float cr[10]={cx,cy,cz,ax,ay,az,dx,dy,dz,dd};
    // ---- stage1: h[k][32q..32q+31] = concat@w1, then BN1+relu -> buf1
    float acc[32];
    #pragma unroll
    for(int i=0;i<32;i++) acc[i]=0.f;
    #pragma unroll
    for(int c=0;c<10;c++){
      const float4* wr = (const float4*)&w1s[c*152 + 40*q];
      float cv = cr[c];
      #pragma unroll
      for(int t=0;t<8;t++){
        float4 wv = wr[t];
        acc[4*t+0]=fmaf(cv,wv.x,acc[4*t+0]);
        acc[4*t+1]=fmaf(cv,wv.y,acc[4*t+1]);
        acc[4*t+2]=fmaf(cv,wv.z,acc[4*t+2]);
        acc[4*t+3]=fmaf(cv,wv.w,acc[4*t+3]);
      }
    }
    #pragma unroll
    for(int t=0;t<8;t++){
      float4 scv = *(const float4*)&s_sc[32*q+4*t];
      float4 shv = *(const float4*)&s_sh[32*q+4*t];
      float4 hv;
      hv.x = fmaxf(0.f, fmaf(acc[4*t+0],scv.x,shv.x));
      hv.y = fmaxf(0.f, fmaf(acc[4*t+1],scv.y,shv.y));
      hv.z = fmaxf(0.f, fmaf(acc[4*t+2],scv.z,shv.z));
      hv.w = fmaxf(0.f, fmaf(acc[4*t+3],scv.w,shv.w));
      *(float4*)&B1p[k*132 + 32*q + 4*t] = hv;
    }
    // ---- stage2: p_c[k][16q..16q+15] = h@w2 (+b2) -> bf16 LDS (p_x low half)
    float pc[16];
    #pragma unroll
    for(int i=0;i<16;i++) pc[i]=0.f;
    #pragma unroll 2
    for(int e4=0;e4<32;++e4){
      float4 hv = *(const float4*)&B1p[k*132 + 4*e4];
      #pragma unroll
      for(int j=0;j<4;j++){
        float hj = (j==0)?hv.x:(j==1)?hv.y:(j==2)?hv.z:hv.w;
        const float4* wr = w2f4 + (4*e4+j)*16 + 4*q;
        #pragma unroll
        for(int t=0;t<4;t++){
          float4 wv = wr[t];
          pc[4*t+0]=fmaf(hj,wv.x,pc[4*t+0]);
          pc[4*t+1]=fmaf(hj,wv.y,pc[4*t+1]);
          pc[4*t+2]=fmaf(hj,wv.z,pc[4*t+2]);
          pc[4*t+3]=fmaf(hj,wv.w,pc[4*t+3]);
        }
      }
    }
    #pragma unroll
    for(int t=0;t<4;t++){
      float4 bv = *(const float4*)&s_b2[16*q+4*t];
      float v0=pc[4*t+0]+bv.x, v1=pc[4*t+1]+bv.y, v2=pc[4*t+2]+bv.z, v3=pc[4*t+3]+bv.w;
      *(uint2*)&B2u[k*68 + 8*q + 2*t] = make_uint2(packbf(v0,v1),packbf(v2,v3));
    }
    // ---- stage3: logits[k][32q..32q+31] = p_x@ws -> buf1 (h is dead)
    float lg[32];
    #pragma unroll
    for(int i=0;i<32;i++) lg[i]=0.f;
    #pragma unroll 1
    for(int dc=0;dc<16;++dc){
      uint4 pu = *(const uint4*)&B2u[k*68 + 4*dc];
      #pragma unroll
      for(int h8=0;h8<4;h8++){
        u32 u = (h8==0)?pu.x:(h8==1)?pu.y:(h8==2)?pu.z:pu.w;
        float plo = bflo(u), phi = bfhi(u);
        int d0 = dc*8 + h8*2;
        const float4* wr0 = wsf4 + (size_t)d0*32 + 8*q;
        #pragma unroll
        for(int t=0;t<8;t++){
          float4 wv = wr0[t];
          lg[4*t+0]=fmaf(plo,wv.x,lg[4*t+0]);
          lg[4*t+1]=fmaf(plo,wv.y,lg[4*t+1]);
          lg[4*t+2]=fmaf(plo,wv.z,lg[4*t+2]);
          lg[4*t+3]=fmaf(plo,wv.w,lg[4*t+3]);
        }
        const float4* wr1 = wr0 + 32;
        #pragma unroll
        for(int t=0;t<8;t++){
          float4 wv = wr1[t];
          lg[4*t+0]=fmaf(phi,wv.x,lg[4*t+0]);
          lg[4*t+1]=fmaf(phi,wv.y,lg[4*t+1]);
          lg[4*t+2]=fmaf(phi,wv.z,lg[4*t+2]);
          lg[4*t+3]=fmaf(phi,wv.w,lg[4*t+3]);
        }
      }
    }
    #pragma unroll
    for(int t=0;t<8;t++){
      *(float4*)&B1p[k*132 + 32*q + 4*t] =
        make_float4(lg[4*t+0],lg[4*t+1],lg[4*t+2],lg[4*t+3]);
    }
    // ---- stage4: softmax over k (per channel) + attention pooling -> s_feat
    #pragma unroll
    for(int half=0;half<2;half++){
      int e = lane + (half<<6);
      float lv[16];
      #pragma unroll
      for(int kk=0;kk<16;kk++) lv[kk]=B1p[kk*132+e];
      float m = lv[0];
      #pragma unroll
      for(int kk=1;kk<16;kk++) m = fmaxf(m,lv[kk]);
      float se=0.f, f=0.f;
      #pragma unroll
      for(int kk=0;kk<16;kk++){
        float ev = __expf(lv[kk]-m);
        se += ev;
        float pxv = __uint_as_float(((u32)B2s[kk*136+e])<<16);
        f = fmaf(ev, pxv, f);
      }
      s_feat[w][e] = f/se;
    }
    // ---- stage5: out[n][lane] = feat@wo  (bo cancels in BN2)
    float od=0.f;
    const float* ft = s_feat[w];
    #pragma unroll 8
    for(int e=0;e<128;e++) od = fmaf(ft[e], wo[e*64+lane], od);
    pre[(size_t)n*64 + lane] = od;
    a_s += od;
    a_q = fmaf(od,od,a_q);
  }
  // block partials for BN2
  s_red[w][lane]      = a_s;
  s_red[w][64+lane]   = a_q;
  __syncthreads();
  if(tid<128){
    float v = s_red[0][tid]+s_red[1][tid]+s_red[2][tid]+s_red[3][tid];
    part2[blockIdx.x*128 + tid] = v;   // [0..63]=sum, [64..127]=sumsq
  }
}

// ---------------- kernel 4: finalize BN2 scale/shift ------------------------
__global__ void k4_fin(const float* __restrict__ part2, const float* __restrict__ g2,
                       const float* __restrict__ be2, float* __restrict__ stats2){
  int t = threadIdx.x; // 64
  float s=0.f, qq=0.f;
  for(int b=0;b<B3G;b++){ s += part2[b*128+t]; qq += part2[b*128+64+t]; }
  float mu  = s/(float)NPTS;
  float var = qq/(float)NPTS - mu*mu;
  float sc = g2[t]*rsqrtf(var+EPSV);
  float sh = be2[t] - mu*sc;
  stats2[t]=sc;
  stats2[64+t]=sh;
}

// ---------------- kernel 5: apply BN2 + relu --------------------------------
__global__ __launch_bounds__(256) void k5_apply(const float* __restrict__ pre,
                                                const float* __restrict__ stats2,
                                                float* __restrict__ out){
  int i = blockIdx.x*256 + threadIdx.x;      // float4 index; 1,048,576 total
  float4 v = ((const float4*)pre)[i];
  int d4 = i & 15;
  float4 sc = ((const float4*)stats2)[d4];
  float4 sh = ((const float4*)(stats2+64))[d4];
  float4 o;
  o.x = fmaxf(0.f, fmaf(v.x,sc.x,sh.x));
  o.y = fmaxf(0.f, fmaf(v.y,sc.y,sh.y));
  o.z = fmaxf(0.f, fmaf(v.z,sc.z,sh.z));
  o.w = fmaxf(0.f, fmaf(v.w,sc.w,sh.w));
  ((float4*)out)[i] = o;
}

extern "C" void kernel_launch(void* const* d_in, const int* in_sizes, int n_in,
                              void* d_out, int out_size, void* d_ws, size_t ws_size,
                              hipStream_t stream){
  (void)in_sizes; (void)n_in; (void)out_size; (void)ws_size;
  const float* p   = (const float*)d_in[0];
  const float* x   = (const float*)d_in[1];
  const float* w1  = (const float*)d_in[2];
  // d_in[3] = b1  : cancels inside BN1
  const float* g1  = (const float*)d_in[4];
  const float* be1 = (const float*)d_in[5];
  const float* w2  = (const float*)d_in[6];
  const float* b2  = (const float*)d_in[7];
  const float* wsm = (const float*)d_in[8];
  const float* wo  = (const float*)d_in[9];
  // d_in[10] = bo : cancels inside BN2
  const float* g2  = (const float*)d_in[11];
  const float* be2 = (const float*)d_in[12];

  float* wsf    = (float*)d_ws;
  float* part1  = wsf + OFF_P1;
  float* stats1 = wsf + OFF_S1;
  float* part2  = wsf + OFF_P2;
  float* stats2 = wsf + OFF_S2;
  float* pre    = wsf + OFF_PRE;
  float* out    = (float*)d_out;

  k1_stats<<<B1G,256,0,stream>>>(p, part1);
  k2_fin  <<<1,128,0,stream>>>(part1, w1, g1, be1, stats1);
  k3_main <<<B3G,256,0,stream>>>(p,x,w2,b2,wsm,wo,w1,stats1,pre,part2);
  k4_fin  <<<1,64,0,stream>>>(part2,g2,be2,stats2);
  k5_apply<<<4096,256,0,stream>>>(pre,stats2,out);
}

// Round 2
// 591.559 us; speedup vs baseline: 17.3186x; 17.3186x over previous
//
#include <hip/hip_runtime.h>
#include <math.h>

#define NPTS 65536
#define EPSV 1e-5f
#define B1G  256   // kernel-1 grid
#define B3G  512   // kernel-3 grid (128 n per block)

// workspace float offsets
#define OFF_P1  0                      // B1G*65
#define OFF_S1  (B1G*65)               // 256 : scale1[128], shift1[128]
#define OFF_P2  (OFF_S1+256)           // B3G*128
#define OFF_S2  (OFF_P2+B3G*128)       // 128 : scale2[64], shift2[64]
#define OFF_PRE (OFF_S2+128)           // NPTS*64

typedef unsigned int u32;
typedef short v8s __attribute__((ext_vector_type(8)));   // 8 bf16 = 4 VGPRs (MFMA A/B frag)
typedef float v4f __attribute__((ext_vector_type(4)));   // MFMA C/D frag

union F8 { v8s v; u32 u[4]; unsigned short s[8]; };

__device__ __forceinline__ u32 f2bf(float f){
  u32 u = __float_as_uint(f);
  return (u + 0x7fffu + ((u>>16)&1u)) >> 16;   // RNE to bf16
}
__device__ __forceinline__ float bf2f(unsigned short s){ return __uint_as_float(((u32)s)<<16); }
__device__ __forceinline__ u32 packbf(float a, float b){ return f2bf(a) | (f2bf(b)<<16); }

// ---------------- kernel 1: Gram-matrix stats over all N*K rows -------------
// Sum_h = (Sum c)@w1 ; Sum_h2 = w1^T (Sum c c^T) w1 (b1 cancels in BN).
__global__ __launch_bounds__(256) void k1_stats(const float* __restrict__ p, float* __restrict__ part1){
  int tid = blockIdx.x*256 + threadIdx.x;
  float M[55]; float s[10];
  #pragma unroll
  for(int i=0;i<55;i++) M[i]=0.f;
  #pragma unroll
  for(int i=0;i<10;i++) s[i]=0.f;
  for(int it=0; it<16; ++it){
    int r = it*65536 + tid;
    int n = r >> 4;
    int kk = r & 15;
    const float* pn = p + (size_t)n*48;
    float cx=pn[0], cy=pn[1], cz=pn[2];
    float ax=pn[kk*3+0], ay=pn[kk*3+1], az=pn[kk*3+2];
    float dx=cx-ax, dy=cy-ay, dz=cz-az;
    float dd = sqrtf(dx*dx+dy*dy+dz*dz);
    float c[10]={cx,cy,cz,ax,ay,az,dx,dy,dz,dd};
    #pragma unroll
    for(int i=0;i<10;i++) s[i]+=c[i];
    int idx=0;
    #pragma unroll
    for(int i=0;i<10;i++){
      #pragma unroll
      for(int j=i;j<10;j++){
        M[idx] = fmaf(c[i],c[j],M[idx]);
        idx++;
      }
    }
  }
  #pragma unroll
  for(int i=0;i<10;i++){
    for(int off=32; off>0; off>>=1) s[i] += __shfl_down(s[i], off, 64);
  }
  #pragma unroll
  for(int i=0;i<55;i++){
    for(int off=32; off>0; off>>=1) M[i] += __shfl_down(M[i], off, 64);
  }
  __shared__ float sm[4][65];
  int lane = threadIdx.x & 63, w = threadIdx.x >> 6;
  if(lane==0){
    #pragma unroll
    for(int i=0;i<10;i++) sm[w][i]=s[i];
    #pragma unroll
    for(int i=0;i<55;i++) sm[w][10+i]=M[i];
  }
  __syncthreads();
  if(threadIdx.x<65){
    float v = sm[0][threadIdx.x]+sm[1][threadIdx.x]+sm[2][threadIdx.x]+sm[3][threadIdx.x];
    part1[blockIdx.x*65 + threadIdx.x] = v;
  }
}

// ---------------- kernel 2: finalize BN1 scale/shift ------------------------
__device__ __forceinline__ int tri_idx(int i,int j){
  int a = i<j? i : j;
  int b = i<j? j : i;
  return 10*a - (a*(a-1))/2 + (b-a);
}
__global__ void k2_fin(const float* __restrict__ part1, const float* __restrict__ w1,
                       const float* __restrict__ g1, const float* __restrict__ be1,
                       float* __restrict__ stats1){
  __shared__ float S[65];
  int t = threadIdx.x; // 128 threads
  if(t<65){
    float a=0.f;
    for(int b=0;b<B1G;b++) a += part1[b*65+t];
    S[t]=a;
  }
  __syncthreads();
  float wc[10];
  #pragma unroll
  for(int c=0;c<10;c++) wc[c]=w1[c*128+t];
  float md=0.f;
  #pragma unroll
  for(int c=0;c<10;c++) md += S[c]*wc[c];
  const float invR = 1.0f/(float)(NPTS*16);
  md *= invR;
  float q=0.f;
  #pragma unroll
  for(int i=0;i<10;i++){
    float ti=0.f;
    #pragma unroll
    for(int j=0;j<10;j++) ti += S[10+tri_idx(i,j)]*wc[j];
    q = fmaf(ti, wc[i], q);
  }
  q *= invR;
  float var = q - md*md;
  float sc = g1[t]*rsqrtf(var+EPSV);
  float sh = be1[t] - md*sc;            // b1 cancels inside BN
  stats1[t]=sc;
  stats1[128+t]=sh;
}

// ---------------- kernel 3: MFMA block-cooperative pipeline -----------------
// 4 waves/block, 4 n per round, 32 rounds (128 n per block).
// Wave w owns channel slice: 32 ch of {h, logits}, 16 ch of {p_c, out}.
// All weights live in VGPRs as 16x16x32 bf16 B-fragments, loaded ONCE.
// lane = 16q + c : c = MFMA row/col index, q = quad (k-group).
__global__ __launch_bounds__(256,2) void k3_main(
    const float* __restrict__ p, const float* __restrict__ x,
    const float* __restrict__ w2, const float* __restrict__ b2,
    const float* __restrict__ wsm, const float* __restrict__ wo,
    const float* __restrict__ w1, const float* __restrict__ stats1,
    float* __restrict__ pre, float* __restrict__ part2)
{
  __shared__ unsigned short s_h [4][16][136];   // h bf16, k-contiguous rows (272B stride)
  __shared__ unsigned short s_px[4][16][136];   // p_x bf16: ch0-63 = p_c, ch64-127 = x
  __shared__ float          s_lg[4][16][132];   // logits fp32
  __shared__ unsigned short s_ft[16][136];      // feat bf16 (16 n batch for stage5 MFMA)

  const int tid  = threadIdx.x;
  const int w    = tid>>6;
  const int lane = tid&63;
  const int q    = lane>>4;
  const int c    = lane&15;

  // ---- load register-resident B fragments (k = kk*32 + q*8 + j) -----------
  v8s Bw1[2], Bw2[4], Bws[2][4], Bwo[4];
  #pragma unroll
  for(int t=0;t<2;t++){
    F8 f;
    #pragma unroll
    for(int j=0;j<8;j++){
      int k = q*8+j;
      f.s[j] = (unsigned short)(k<10 ? f2bf(w1[k*128 + 32*w + 16*t + c]) : 0);
    }
    Bw1[t]=f.v;
  }
  #pragma unroll
  for(int kk=0;kk<4;kk++){
    F8 f;
    #pragma unroll
    for(int j=0;j<8;j++) f.s[j]=(unsigned short)f2bf(w2[(kk*32+q*8+j)*64 + 16*w + c]);
    Bw2[kk]=f.v;
  }
  #pragma unroll
  for(int t=0;t<2;t++){
    #pragma unroll
    for(int kk=0;kk<4;kk++){
      F8 f;
      #pragma unroll
      for(int j=0;j<8;j++) f.s[j]=(unsigned short)f2bf(wsm[(kk*32+q*8+j)*128 + 32*w + 16*t + c]);
      Bws[t][kk]=f.v;
    }
  }
  #pragma unroll
  for(int kk=0;kk<4;kk++){
    F8 f;
    #pragma unroll
    for(int j=0;j<8;j++) f.s[j]=(unsigned short)f2bf(wo[(kk*32+q*8+j)*64 + 16*w + c]);
    Bwo[kk]=f.v;
  }
  const float sc1a = stats1[32*w+c],    sh1a = stats1[128+32*w+c];
  const float sc1b = stats1[32*w+16+c], sh1b = stats1[128+32*w+16+c];
  const float b2v  = b2[16*w+c];

  float a_s=0.f, a_q=0.f;
  const int base0 = blockIdx.x*128;

  for(int r=0;r<32;++r){
    const int base = base0 + 4*r;

    // ---- x rows -> s_px[ch 64..127] bf16 (coalesced float4 loads) ---------
    const float4* xg = (const float4*)(x + (size_t)base*1024);
    #pragma unroll
    for(int rr=0;rr<4;rr++){
      int f = tid + 256*rr;
      float4 v = xg[f];
      int nl = f>>8, rem = f&255, pt = rem>>4, d4 = rem&15;
      *(uint2*)&s_px[nl][pt][64+4*d4] = make_uint2(packbf(v.x,v.y), packbf(v.z,v.w));
    }

    // ---- stage1: h = concat@w1 -> BN1 -> relu -> s_h (bf16) ---------------
    #pragma unroll
    for(int n0=0;n0<4;n0++){
      const float* pn = p + (size_t)(base+n0)*48;
      float cx=pn[0], cy=pn[1], cz=pn[2];
      float ax=pn[3*c], ay=pn[3*c+1], az=pn[3*c+2];   // lane's point m=c
      float dx=cx-ax, dy=cy-ay, dz=cz-az;
      float dd=sqrtf(dx*dx+dy*dy+dz*dz);
      float cr[10]={cx,cy,cz,ax,ay,az,dx,dy,dz,dd};
      F8 fa;
      #pragma unroll
      for(int j=0;j<8;j++){ int k=q*8+j; fa.s[j]=(unsigned short)(k<10 ? f2bf(cr[k]) : 0); }
      v4f z={0.f,0.f,0.f,0.f};
      v4f d0 = __builtin_amdgcn_mfma_f32_16x16x32_bf16(fa.v, Bw1[0], z, 0,0,0);
      v4f d1 = __builtin_amdgcn_mfma_f32_16x16x32_bf16(fa.v, Bw1[1], z, 0,0,0);
      #pragma unroll
      for(int i=0;i<4;i++){
        float v0 = fmaxf(0.f, fmaf(d0[i], sc1a, sh1a));
        float v1 = fmaxf(0.f, fmaf(d1[i], sc1b, sh1b));
        s_h[n0][4*q+i][32*w+c]    = (unsigned short)f2bf(v0);
        s_h[n0][4*q+i][32*w+16+c] = (unsigned short)f2bf(v1);
      }
    }
    __syncthreads();

    // ---- stage2: p_c = h@w2 + b2 -> s_px[ch 0..63] bf16 -------------------
    #pragma unroll
    for(int n0=0;n0<4;n0++){
      const v8s* Ar = (const v8s*)&s_h[n0][c][0];
      v4f acc={0.f,0.f,0.f,0.f};
      #pragma unroll
      for(int kk=0;kk<4;kk++)
        acc = __builtin_amdgcn_mfma_f32_16x16x32_bf16(Ar[kk*4+q], Bw2[kk], acc, 0,0,0);
      #pragma unroll
      for(int i=0;i<4;i++) s_px[n0][4*q+i][16*w+c] = (unsigned short)f2bf(acc[i] + b2v);
    }
    __syncthreads();

    // ---- stage3: logits = p_x@ws -> s_lg fp32 -----------------------------
    #pragma unroll
    for(int n0=0;n0<4;n0++){
      const v8s* Ar = (const v8s*)&s_px[n0][c][0];
      v4f l0={0.f,0.f,0.f,0.f}, l1={0.f,0.f,0.f,0.f};
      #pragma unroll
      for(int kk=0;kk<4;kk++){
        v8s a = Ar[kk*4+q];
        l0 = __builtin_amdgcn_mfma_f32_16x16x32_bf16(a, Bws[0][kk], l0, 0,0,0);
        l1 = __builtin_amdgcn_mfma_f32_16x16x32_bf16(a, Bws[1][kk], l1, 0,0,0);
      }
      #pragma unroll
      for(int i=0;i<4;i++){
        s_lg[n0][4*q+i][32*w+c]    = l0[i];
        s_lg[n0][4*q+i][32*w+16+c] = l1[i];
      }
    }
    __syncthreads();

    // ---- stage4: softmax over points + attention pool; wave w owns n0=w ---
    {
      const int slot = (r&3)*4 + w;
      #pragma unroll
      for(int hh=0;hh<2;hh++){
        const int ch = lane + 64*hh;
        float lv[16];
        #pragma unroll
        for(int pt=0;pt<16;pt++) lv[pt] = s_lg[w][pt][ch];
        float m = lv[0];
        #pragma unroll
        for(int pt=1;pt<16;pt++) m = fmaxf(m, lv[pt]);
        float se=0.f, fe=0.f;
        #pragma unroll
        for(int pt=0;pt<16;pt++){
          float e = __expf(lv[pt]-m);
          se += e;
          fe = fmaf(e, bf2f(s_px[w][pt][ch]), fe);
        }
        s_ft[slot][ch] = (unsigned short)f2bf(fe/se);
      }
    }
    __syncthreads();   // protects s_ft before stage5 AND s_px/s_lg before next round

    // ---- stage5: out = feat@wo for 16 buffered n (every 4 rounds) ---------
    if((r&3)==3){
      const v8s* Ar = (const v8s*)&s_ft[c][0];
      v4f o={0.f,0.f,0.f,0.f};
      #pragma unroll
      for(int kk=0;kk<4;kk++)
        o = __builtin_amdgcn_mfma_f32_16x16x32_bf16(Ar[kk*4+q], Bwo[kk], o, 0,0,0);
      const int nb16 = base0 + (r>>2)*16;
      #pragma unroll
      for(int i=0;i<4;i++){
        float val = o[i];
        pre[(size_t)(nb16 + 4*q + i)*64 + 16*w + c] = val;
        a_s += val;
        a_q = fmaf(val,val,a_q);
      }
    }
  }

  // ---- BN2 partials: reduce over quads (same d = 16w+c across q) ----------
  a_s += __shfl_xor(a_s, 16, 64); a_s += __shfl_xor(a_s, 32, 64);
  a_q += __shfl_xor(a_q, 16, 64); a_q += __shfl_xor(a_q, 32, 64);
  if(q==0){
    part2[blockIdx.x*128 + 16*w + c]      = a_s;
    part2[blockIdx.x*128 + 64 + 16*w + c] = a_q;
  }
}

// ---------------- kernel 4: finalize BN2 scale/shift ------------------------
__global__ void k4_fin(const float* __restrict__ part2, const float* __restrict__ g2,
                       const float* __restrict__ be2, float* __restrict__ stats2){
  int t = threadIdx.x; // 64
  float s=0.f, qq=0.f;
  for(int b=0;b<B3G;b++){ s += part2[b*128+t]; qq += part2[b*128+64+t]; }
  float mu  = s/(float)NPTS;
  float var = qq/(float)NPTS - mu*mu;
  float sc = g2[t]*rsqrtf(var+EPSV);
  float sh = be2[t] - mu*sc;            // bo cancels inside BN
  stats2[t]=sc;
  stats2[64+t]=sh;
}

// ---------------- kernel 5: apply BN2 + relu --------------------------------
__global__ __launch_bounds__(256) void k5_apply(const float* __restrict__ pre,
                                                const float* __restrict__ stats2,
                                                float* __restrict__ out){
  int i = blockIdx.x*256 + threadIdx.x;      // float4 index; 1,048,576 total
  float4 v = ((const float4*)pre)[i];
  int d4 = i & 15;
  float4 sc = ((const float4*)stats2)[d4];
  float4 sh = ((const float4*)(stats2+64))[d4];
  float4 o;
  o.x = fmaxf(0.f, fmaf(v.x,sc.x,sh.x));
  o.y = fmaxf(0.f, fmaf(v.y,sc.y,sh.y));
  o.z = fmaxf(0.f, fmaf(v.z,sc.z,sh.z));
  o.w = fmaxf(0.f, fmaf(v.w,sc.w,sh.w));
  ((float4*)out)[i] = o;
}

extern "C" void kernel_launch(void* const* d_in, const int* in_sizes, int n_in,
                              void* d_out, int out_size, void* d_ws, size_t ws_size,
                              hipStream_t stream){
  (void)in_sizes; (void)n_in; (void)out_size; (void)ws_size;
  const float* p   = (const float*)d_in[0];
  const float* x   = (const float*)d_in[1];
  const float* w1  = (const float*)d_in[2];
  // d_in[3] = b1  : cancels inside BN1
  const float* g1  = (const float*)d_in[4];
  const float* be1 = (const float*)d_in[5];
  const float* w2  = (const float*)d_in[6];
  const float* b2  = (const float*)d_in[7];
  const float* wsm = (const float*)d_in[8];
  const float* wo  = (const float*)d_in[9];
  // d_in[10] = bo : cancels inside BN2
  const float* g2  = (const float*)d_in[11];
  const float* be2 = (const float*)d_in[12];

  float* wsf    = (float*)d_ws;
  float* part1  = wsf + OFF_P1;
  float* stats1 = wsf + OFF_S1;
  float* part2  = wsf + OFF_P2;
  float* stats2 = wsf + OFF_S2;
  float* pre    = wsf + OFF_PRE;
  float* out    = (float*)d_out;

  k1_stats<<<B1G,256,0,stream>>>(p, part1);
  k2_fin  <<<1,128,0,stream>>>(part1, w1, g1, be1, stats1);
  k3_main <<<B3G,256,0,stream>>>(p,x,w2,b2,wsm,wo,w1,stats1,pre,part2);
  k4_fin  <<<1,64,0,stream>>>(part2,g2,be2,stats2);
  k5_apply<<<4096,256,0,stream>>>(pre,stats2,out);
}